// Round 4
// baseline (877.511 us; speedup 1.0000x reference)
//
#include <hip/hip_runtime.h>
#include <hip/hip_bf16.h>
#include <math.h>

constexpr int LEVELS_ = 9;
constexpr int N_NODES_ = 87381;
constexpr int HS = 256;
constexpr int N_HEADS_ = 8;

typedef __attribute__((ext_vector_type(8))) short bf16x8;
typedef __attribute__((ext_vector_type(4))) float f32x4;
typedef __attribute__((ext_vector_type(4))) float float4v;

__device__ __forceinline__ short f2bf(float f) {
    union { float f; unsigned u; } a; a.f = f;
    unsigned r = (a.u + 0x7fff + ((a.u >> 16) & 1)) >> 16;
    return (short)r;
}
__device__ __forceinline__ float bf2f(short s) {
    union { unsigned u; float f; } a; a.u = ((unsigned)(unsigned short)s) << 16;
    return a.f;
}
// fast transcendentals: v_exp_f32-based (error ~1e-6 rel, << bf16 rounding)
__device__ __forceinline__ float sigm(float x) { return 1.f / (1.f + __expf(-x)); }
__device__ __forceinline__ float ftanh(float x) {
    float e = __expf(-2.f * fabsf(x));
    float t = (1.f - e) / (1.f + e);
    return copysignf(t, x);
}

// async global->LDS, 16B per lane; LDS dest is wave-uniform base (+lane*16 by HW)
__device__ __forceinline__ void gl_lds16(const short* g, short* l) {
    __builtin_amdgcn_global_load_lds(
        (const __attribute__((address_space(1))) void*)g,
        (__attribute__((address_space(3))) void*)l, 16, 0, 0);
}

// bijective XCD-aware remap (m204)
__device__ __forceinline__ int xcd_swizzle(int flat, int nwg) {
    int q = nwg >> 3, r = nwg & 7;
    int xcd = flat & 7, idx = flat >> 3;
    int base = (xcd < r) ? xcd * (q + 1) : r * (q + 1) + (xcd - r) * q;
    return base + idx;
}

// device-scope grid barrier (grid must be fully co-resident; <=256 blocks).
// counters pre-zeroed by prep_weights (stream-ordered earlier same iteration).
__device__ __forceinline__ void gridbar(int* c, int nb) {
    __syncthreads();
    if (threadIdx.x == 0) {
        __threadfence();                         // release (L2 writeback)
        atomicAdd(c, 1);
        while (atomicAdd(c, 0) < nb) __builtin_amdgcn_s_sleep(2);
        __threadfence();                         // acquire (invalidate)
    }
    __syncthreads();
}

// ---------------------------------------------------------------------------
// Generic bf16 GEMM: C[M,N] = A @ Bt^T + bias (+Cadd), bf16 or f32 out.
// Optional dual output: cols >= Nsplit go to Cout2 (width N-Nsplit).
// 128x128 tile, BK=64, DOUBLE-BUFFERED 2-phase pipeline (T3 minimum recipe):
// stage(t+1) issued BEFORE compute(t); single __syncthreads per tile (its
// auto vmcnt(0) lands after compute -> HBM latency hidden under MFMA).
// REQUIREMENT: A readable for ceil(M/128)*128 rows; N%128==0; K%64==0.
// ---------------------------------------------------------------------------
__global__ __launch_bounds__(256) void gemm_bf16(
    const short* __restrict__ A, const short* __restrict__ Bt,
    const float* __restrict__ bias, const short* __restrict__ Cadd,
    void* __restrict__ Cout, int M, int N, int Kd, int out_bf16,
    short* __restrict__ Cout2, int Nsplit)
{
    __shared__ __align__(16) short smem[32768];   // 2 x (As 8192 | Bs 8192)

    const int tid = threadIdx.x;
    const int lane = tid & 63;
    const int w = tid >> 6;
    const int gx = gridDim.x;
    const int sw = xcd_swizzle(blockIdx.y * gx + blockIdx.x, gx * gridDim.y);
    const int row0 = (sw / gx) * 128;
    const int col0 = (sw % gx) * 128;
    const int wm = (w >> 1) * 64;
    const int wn = (w & 1) * 64;
    const int q = lane >> 4;
    const int mr = lane & 15;

    const int srl = lane >> 3;
    const int scs = ((lane & 7) ^ srl) * 8;

    auto stage = [&](int b, int k0) {
        short* As = smem + b * 16384;
        short* Bs = As + 8192;
        #pragma unroll
        for (int i = 0; i < 4; ++i) {
            int s = w * 4 + i;
            int r = s * 8 + srl;
            gl_lds16(A + (size_t)(row0 + r) * Kd + k0 + scs, As + s * 512);
            gl_lds16(Bt + (size_t)(col0 + r) * Kd + k0 + scs, Bs + s * 512);
        }
    };

    f32x4 acc[4][4];
    #pragma unroll
    for (int i = 0; i < 4; i++)
        #pragma unroll
        for (int j = 0; j < 4; j++) acc[i][j] = (f32x4){0.f, 0.f, 0.f, 0.f};

    stage(0, 0);
    __syncthreads();
    const int nk = Kd >> 6;
    for (int t = 0; t < nk; ++t) {
        if (t + 1 < nk) stage((t + 1) & 1, (t + 1) << 6);
        const short* As = smem + (t & 1) * 16384;
        const short* Bs = As + 8192;
        #pragma unroll
        for (int h = 0; h < 2; ++h) {
            bf16x8 af[4], bfr[4];
            #pragma unroll
            for (int i = 0; i < 4; ++i) {
                int r = wm + i * 16 + mr;
                af[i] = *(const bf16x8*)(As + r * 64 + ((h * 4 + q) ^ (mr & 7)) * 8);
            }
            #pragma unroll
            for (int j = 0; j < 4; ++j) {
                int r = wn + j * 16 + mr;
                bfr[j] = *(const bf16x8*)(Bs + r * 64 + ((h * 4 + q) ^ (mr & 7)) * 8);
            }
            #pragma unroll
            for (int i = 0; i < 4; ++i)
                #pragma unroll
                for (int j = 0; j < 4; ++j)
                    acc[i][j] = __builtin_amdgcn_mfma_f32_16x16x32_bf16(
                        af[i], bfr[j], acc[i][j], 0, 0, 0);
        }
        __syncthreads();
    }

    // resolve destination (dual-output support)
    short* dst;
    int width, colbase;
    if (Cout2 && col0 >= Nsplit) { dst = Cout2; colbase = col0 - Nsplit; width = N - Nsplit; }
    else { dst = (short*)Cout; colbase = col0; width = Cout2 ? Nsplit : N; }

    if (out_bf16) {
        short* Cs = smem;   // 128x128, fits in buffer 0 region
        #pragma unroll
        for (int j = 0; j < 4; ++j) {
            int col = wn + j * 16 + mr;
            float bv = bias ? bias[col0 + col] : 0.f;
            #pragma unroll
            for (int i = 0; i < 4; ++i) {
                #pragma unroll
                for (int r = 0; r < 4; ++r) {
                    int lr = wm + i * 16 + q * 4 + r;
                    float v = acc[i][j][r] + bv;
                    if (Cadd && row0 + lr < M)
                        v += bf2f(Cadd[(size_t)(row0 + lr) * width + colbase + col]);
                    Cs[lr * 128 + col] = f2bf(v);
                }
            }
        }
        __syncthreads();
        #pragma unroll
        for (int i = 0; i < 8; ++i) {
            int chunk = i * 256 + tid;
            int lr = chunk >> 4;
            int c8 = (chunk & 15) * 8;
            if (row0 + lr < M)
                *(bf16x8*)(dst + (size_t)(row0 + lr) * width + colbase + c8) =
                    *(const bf16x8*)(Cs + lr * 128 + c8);
        }
    } else {
        #pragma unroll
        for (int j = 0; j < 4; ++j) {
            int col = col0 + wn + j * 16 + mr;
            float bv = bias ? bias[col] : 0.f;
            #pragma unroll
            for (int i = 0; i < 4; ++i) {
                #pragma unroll
                for (int r = 0; r < 4; ++r) {
                    int grow = row0 + wm + i * 16 + q * 4 + r;
                    if (grow < M) {
                        size_t off = (size_t)grow * N + col;
                        float v = acc[i][j][r] + bv;
                        if (Cadd) v += bf2f(Cadd[off]);
                        ((float*)Cout)[off] = v;
                    }
                }
            }
        }
    }
}

// ---------------------------------------------------------------------------
// GEMM + fused LSTM cell. Bt is GATE-GROUPED: col = grp*128 + gate*32 + d,
// hidden dim = grp*32 + d, gates [i,o,u,f]. c_child==nullptr -> leaf
// (f-gate MFMAs + staging skipped). Double-buffered pipeline as above.
// ---------------------------------------------------------------------------
__global__ __launch_bounds__(256) void gemm_cell(
    const short* __restrict__ A, const short* __restrict__ Bt,
    const float* __restrict__ bias, const short* __restrict__ Cadd,
    const float* __restrict__ c_child,
    float* __restrict__ h_out, float* __restrict__ c_out,
    short* __restrict__ hb_out, int M)
{
    __shared__ __align__(16) short smem[32768];   // dbuf; Cs (128x136) overlays

    const int tid = threadIdx.x;
    const int lane = tid & 63;
    const int w = tid >> 6;
    const int gx = gridDim.x;
    const int sw = xcd_swizzle(blockIdx.y * gx + blockIdx.x, gx * gridDim.y);
    const int row0 = (sw / gx) * 128;
    const int bxs = sw % gx;
    const int col0 = bxs * 128;
    const int wm = (w >> 1) * 64;
    const int wn = (w & 1) * 64;
    const int q = lane >> 4;
    const int mr = lane & 15;

    const int srl = lane >> 3;
    const int scs = ((lane & 7) ^ srl) * 8;

    const bool leaf = (c_child == nullptr);
    const int jn = (leaf && wn == 64) ? 2 : 4;   // skip f-gate tiles for leaves

    auto stage = [&](int b, int k0) {
        short* As = smem + b * 16384;
        short* Bs = As + 8192;
        #pragma unroll
        for (int i = 0; i < 4; ++i) {
            int s = w * 4 + i;
            int r = s * 8 + srl;
            gl_lds16(A + (size_t)(row0 + r) * 256 + k0 + scs, As + s * 512);
            if (!(leaf && s >= 12))   // Bs rows 96..127 = f-gate cols: unused
                gl_lds16(Bt + (size_t)(col0 + r) * 256 + k0 + scs, Bs + s * 512);
        }
    };

    f32x4 acc[4][4];
    #pragma unroll
    for (int i = 0; i < 4; i++)
        #pragma unroll
        for (int j = 0; j < 4; j++) acc[i][j] = (f32x4){0.f, 0.f, 0.f, 0.f};

    stage(0, 0);
    __syncthreads();
    for (int t = 0; t < 4; ++t) {
        if (t + 1 < 4) stage((t + 1) & 1, (t + 1) << 6);
        const short* As = smem + (t & 1) * 16384;
        const short* Bs = As + 8192;
        #pragma unroll
        for (int h = 0; h < 2; ++h) {
            bf16x8 af[4], bfr[4];
            #pragma unroll
            for (int i = 0; i < 4; ++i) {
                int r = wm + i * 16 + mr;
                af[i] = *(const bf16x8*)(As + r * 64 + ((h * 4 + q) ^ (mr & 7)) * 8);
            }
            #pragma unroll
            for (int j = 0; j < 4; ++j)
                if (j < jn) {
                    int r = wn + j * 16 + mr;
                    bfr[j] = *(const bf16x8*)(Bs + r * 64 + ((h * 4 + q) ^ (mr & 7)) * 8);
                }
            #pragma unroll
            for (int i = 0; i < 4; ++i)
                #pragma unroll
                for (int j = 0; j < 4; ++j)
                    if (j < jn)
                        acc[i][j] = __builtin_amdgcn_mfma_f32_16x16x32_bf16(
                            af[i], bfr[j], acc[i][j], 0, 0, 0);
        }
        __syncthreads();
    }

    // preacts -> Cs (bf16, stride 136 to spread 4-gate strided reads)
    short* Cs = smem;
    #pragma unroll
    for (int j = 0; j < 4; ++j) {
        int col = wn + j * 16 + mr;
        float bv = bias[col0 + col];
        #pragma unroll
        for (int i = 0; i < 4; ++i) {
            #pragma unroll
            for (int r = 0; r < 4; ++r) {
                int lr = wm + i * 16 + q * 4 + r;
                float v = acc[i][j][r] + bv;
                if (Cadd && row0 + lr < M)
                    v += bf2f(Cadd[(size_t)(row0 + lr) * 1024 + col0 + col]);
                Cs[lr * 136 + col] = f2bf(v);
            }
        }
    }
    __syncthreads();

    const int hd0 = bxs * 32;
    #pragma unroll 1
    for (int it = 0; it < 2; ++it) {
        int chunk = it * 256 + tid;       // 512 chunks: 128 rows x 4 d8-slots
        int row = chunk >> 2;
        int d8 = (chunk & 3) * 8;
        int gp = row0 + row;
        if (gp < M) {
            bf16x8 vi = *(const bf16x8*)(Cs + row * 136 + d8);
            bf16x8 vo = *(const bf16x8*)(Cs + row * 136 + 32 + d8);
            bf16x8 vu = *(const bf16x8*)(Cs + row * 136 + 64 + d8);
            float fc[8] = {0.f, 0.f, 0.f, 0.f, 0.f, 0.f, 0.f, 0.f};
            if (!leaf) {
                bf16x8 vf = *(const bf16x8*)(Cs + row * 136 + 96 + d8);
                #pragma unroll
                for (int c = 0; c < 4; ++c) {
                    const float* cp = c_child + (size_t)(4 * gp + c) * 256 + hd0 + d8;
                    float4v a = *(const float4v*)cp;
                    float4v b = *(const float4v*)(cp + 4);
                    #pragma unroll
                    for (int e = 0; e < 4; ++e) { fc[e] += a[e]; fc[4 + e] += b[e]; }
                }
                #pragma unroll
                for (int e = 0; e < 8; ++e) fc[e] *= sigm(bf2f(vf[e]));
            }
            float4v hv[2], cv[2];
            bf16x8 hbv;
            #pragma unroll
            for (int e = 0; e < 8; ++e) {
                float cn = sigm(bf2f(vi[e])) * ftanh(bf2f(vu[e])) + fc[e];
                float hn = sigm(bf2f(vo[e])) * ftanh(cn);
                hv[e >> 2][e & 3] = hn;
                cv[e >> 2][e & 3] = cn;
                hbv[e] = f2bf(hn);
            }
            size_t o = (size_t)gp * 256 + hd0 + d8;
            *(float4v*)(h_out + o) = hv[0]; *(float4v*)(h_out + o + 4) = hv[1];
            *(float4v*)(c_out + o) = cv[0]; *(float4v*)(c_out + o + 4) = cv[1];
            *(bf16x8*)(hb_out + o) = hbv;
        }
    }
}

// ---------------------------------------------------------------------------
// KV GEMM + fused attention. B3t HEAD-GROUPED: col = head*64 + kv*32 + d.
// Block (bx,by): child rows by*128 (=32 parents), heads 2bx,2bx+1 (K+V).
// Double-buffered pipeline.
// ---------------------------------------------------------------------------
__global__ __launch_bounds__(256) void kv_attn(
    const short* __restrict__ A,       // hb + sc*256 (children)
    const short* __restrict__ B3t,     // grouped [512][256]
    const float* __restrict__ bias_kv, // grouped [512]
    const short* __restrict__ qb_lvl,  // qb + s0*256
    short* __restrict__ outb)
{
    __shared__ __align__(16) short smem[32768 + 2048]; // dbuf -> Cs ; sh_o
    short* sh_o = smem + 32768;

    const int tid = threadIdx.x;
    const int lane = tid & 63;
    const int w = tid >> 6;
    const int gx = gridDim.x;   // 4
    const int sw = xcd_swizzle(blockIdx.y * gx + blockIdx.x, gx * gridDim.y);
    const int byq = sw / gx;
    const int colb = sw % gx;          // heads 2*colb, 2*colb+1
    const int row0 = byq * 128;
    const int col0 = colb * 128;
    const int wm = (w >> 1) * 64;
    const int wn = (w & 1) * 64;
    const int q = lane >> 4;
    const int mr = lane & 15;

    const int srl = lane >> 3;
    const int scs = ((lane & 7) ^ srl) * 8;

    auto stage = [&](int b, int k0) {
        short* As = smem + b * 16384;
        short* Bs = As + 8192;
        #pragma unroll
        for (int i = 0; i < 4; ++i) {
            int s = w * 4 + i;
            int r = s * 8 + srl;
            gl_lds16(A + (size_t)(row0 + r) * 256 + k0 + scs, As + s * 512);
            gl_lds16(B3t + (size_t)(col0 + r) * 256 + k0 + scs, Bs + s * 512);
        }
    };

    f32x4 acc[4][4];
    #pragma unroll
    for (int i = 0; i < 4; i++)
        #pragma unroll
        for (int j = 0; j < 4; j++) acc[i][j] = (f32x4){0.f, 0.f, 0.f, 0.f};

    stage(0, 0);
    __syncthreads();
    for (int t = 0; t < 4; ++t) {
        if (t + 1 < 4) stage((t + 1) & 1, (t + 1) << 6);
        const short* As = smem + (t & 1) * 16384;
        const short* Bs = As + 8192;
        #pragma unroll
        for (int h = 0; h < 2; ++h) {
            bf16x8 af[4], bfr[4];
            #pragma unroll
            for (int i = 0; i < 4; ++i) {
                int r = wm + i * 16 + mr;
                af[i] = *(const bf16x8*)(As + r * 64 + ((h * 4 + q) ^ (mr & 7)) * 8);
            }
            #pragma unroll
            for (int j = 0; j < 4; ++j) {
                int r = wn + j * 16 + mr;
                bfr[j] = *(const bf16x8*)(Bs + r * 64 + ((h * 4 + q) ^ (mr & 7)) * 8);
            }
            #pragma unroll
            for (int i = 0; i < 4; ++i)
                #pragma unroll
                for (int j = 0; j < 4; ++j)
                    acc[i][j] = __builtin_amdgcn_mfma_f32_16x16x32_bf16(
                        af[i], bfr[j], acc[i][j], 0, 0, 0);
        }
        __syncthreads();
    }

    // KV tile -> Cs (bf16, 128x128)
    short* Cs = smem;
    #pragma unroll
    for (int j = 0; j < 4; ++j) {
        int col = wn + j * 16 + mr;
        float bv = bias_kv[col0 + col];
        #pragma unroll
        for (int i = 0; i < 4; ++i) {
            #pragma unroll
            for (int r = 0; r < 4; ++r) {
                int lr = wm + i * 16 + q * 4 + r;
                Cs[lr * 128 + col] = f2bf(acc[i][j][r] + bv);
            }
        }
    }
    __syncthreads();

    // attention: 32 parents x 2 heads = 64 pairs, 32 lanes each
    const int p0 = byq * 32;
    const int grp0 = tid >> 5;
    const int l32 = tid & 31;
    #pragma unroll 1
    for (int it = 0; it < 8; ++it) {
        int pair = it * 8 + grp0;         // 0..63
        int pl = pair >> 1, hh = pair & 1;
        float qv = bf2f(qb_lvl[(size_t)(p0 + pl) * 256 + (colb * 2 + hh) * 32 + l32]);
        float logit[4];
        #pragma unroll
        for (int c = 0; c < 4; ++c) {
            float pch = qv * bf2f(Cs[(4 * pl + c) * 128 + hh * 64 + l32]);
            #pragma unroll
            for (int off = 16; off >= 1; off >>= 1)
                pch += __shfl_xor(pch, off, 32);
            logit[c] = pch * 0.17677669529663687f;
        }
        float mx = fmaxf(fmaxf(logit[0], logit[1]), fmaxf(logit[2], logit[3]));
        float e[4], s = 0.f;
        #pragma unroll
        for (int c = 0; c < 4; ++c) { e[c] = __expf(logit[c] - mx); s += e[c]; }
        float inv = 1.f / s;
        float o = 0.f;
        #pragma unroll
        for (int c = 0; c < 4; ++c)
            o += (e[c] * inv) * bf2f(Cs[(4 * pl + c) * 128 + hh * 64 + 32 + l32]);
        sh_o[pl * 64 + hh * 32 + l32] = f2bf(o);
    }
    __syncthreads();
    {
        int r = tid >> 3, c8 = (tid & 7) * 8;    // 32 rows x 64 cols
        *(bf16x8*)(outb + (size_t)(p0 + r) * 256 + colb * 64 + c8) =
            *(const bf16x8*)(sh_o + r * 64 + c8);
    }
}

// ---------------------------------------------------------------------------
// MERGED fused kernel for levels 5..0 (grouped layouts). ONE launch, grid=128
// blocks (all co-resident), device-scope grid barrier between levels.
// NOTE: c_all / h_all / hb intentionally NOT __restrict__ (read+write alias
// across levels within this kernel).
// ---------------------------------------------------------------------------
__global__ __launch_bounds__(256) void level_fused_all(
    short* hb, float* c_all,
    const short* __restrict__ qb, const short* __restrict__ xi,
    const short* __restrict__ B3t, const short* __restrict__ Wlt,
    const short* __restrict__ Bt2,
    const float* __restrict__ bias_kv, const float* __restrict__ bl,
    const float* __restrict__ biasU,
    float* h_all, int* bar)
{
    __shared__ __align__(16) char smem[50176];
    short* sh_h    = (short*)smem;             // 32 x 264
    short* sh_kv   = (short*)(smem + 16896);   // 32 x 520 (grouped cols)
    short* sh_out  = (short*)smem;             // 16 x 264 (reuse sh_h)
    short* sh_ha   = (short*)(smem + 8448);    // 16 x 264
    float* sh_iouf = (float*)(smem + 16896);   // 8 x 1024 (grouped cols)

    const int tid = threadIdx.x;
    const int lane = tid & 63;
    const int w = tid >> 6;
    const int q = lane >> 4;
    const int mr = lane & 15;

    static constexpr int st[7] = {0, 1, 5, 21, 85, 341, 1365};

    for (int l = 5; l >= 0; --l) {
        const int n  = 1 << (2 * l);
        const int s0 = st[l];
        const int sc = st[l + 1];
        const int p0 = blockIdx.x * 8;
        if (p0 < n) {
            const int np = (n - p0 < 8) ? (n - p0) : 8;
            const int nch = 4 * np;

            // phase 0: stage children h
            #pragma unroll
            for (int i = 0; i < 4; ++i) {
                int chunk = i * 256 + tid;
                int r = chunk >> 5;
                int c8 = (chunk & 31) * 8;
                bf16x8 v = {};
                if (r < nch) v = *(const bf16x8*)(hb + (size_t)(sc + 4 * p0 + r) * 256 + c8);
                *(bf16x8*)(sh_h + r * 264 + c8) = v;
            }
            __syncthreads();

            // phase 1: KV[32x512] = sh_h @ B3t^T + bias_kv (grouped cols)
            {
                f32x4 acc[2][8];
                #pragma unroll
                for (int rt = 0; rt < 2; ++rt)
                    #pragma unroll
                    for (int ct = 0; ct < 8; ++ct) acc[rt][ct] = (f32x4){0.f, 0.f, 0.f, 0.f};
                #pragma unroll 1
                for (int k0 = 0; k0 < 256; k0 += 32) {
                    bf16x8 a0 = *(const bf16x8*)(sh_h + mr * 264 + k0 + q * 8);
                    bf16x8 a1 = *(const bf16x8*)(sh_h + (16 + mr) * 264 + k0 + q * 8);
                    #pragma unroll
                    for (int ct = 0; ct < 8; ++ct) {
                        int col = w * 128 + ct * 16 + mr;
                        bf16x8 b = *(const bf16x8*)(B3t + (size_t)col * 256 + k0 + q * 8);
                        acc[0][ct] = __builtin_amdgcn_mfma_f32_16x16x32_bf16(a0, b, acc[0][ct], 0, 0, 0);
                        acc[1][ct] = __builtin_amdgcn_mfma_f32_16x16x32_bf16(a1, b, acc[1][ct], 0, 0, 0);
                    }
                }
                #pragma unroll
                for (int ct = 0; ct < 8; ++ct) {
                    int col = w * 128 + ct * 16 + mr;
                    float bv = bias_kv[col];
                    #pragma unroll
                    for (int rt = 0; rt < 2; ++rt)
                        #pragma unroll
                        for (int r = 0; r < 4; ++r) {
                            int row = rt * 16 + q * 4 + r;
                            sh_kv[row * 520 + col] = f2bf(acc[rt][ct][r] + bv);
                        }
                }
            }
            __syncthreads();

            // phase 2: attention (K at head*64, V at head*64+32) -> sh_out
            {
                const int grp0 = tid >> 5;
                const int l32 = tid & 31;
                #pragma unroll 1
                for (int it = 0; it < 8; ++it) {
                    int grp = it * 8 + grp0;
                    int node = grp >> 3, head = grp & 7;
                    if (node < np) {
                        float qv = bf2f(qb[(size_t)(s0 + p0 + node) * 256 + head * 32 + l32]);
                        float logit[4];
                        #pragma unroll
                        for (int c = 0; c < 4; ++c) {
                            float p = qv * bf2f(sh_kv[(4 * node + c) * 520 + head * 64 + l32]);
                            #pragma unroll
                            for (int off = 16; off >= 1; off >>= 1)
                                p += __shfl_xor(p, off, 32);
                            logit[c] = p * 0.17677669529663687f;
                        }
                        float mx = fmaxf(fmaxf(logit[0], logit[1]), fmaxf(logit[2], logit[3]));
                        float e[4], s = 0.f;
                        #pragma unroll
                        for (int c = 0; c < 4; ++c) { e[c] = __expf(logit[c] - mx); s += e[c]; }
                        float inv = 1.f / s;
                        float o = 0.f;
                        #pragma unroll
                        for (int c = 0; c < 4; ++c)
                            o += (e[c] * inv) * bf2f(sh_kv[(4 * node + c) * 520 + head * 64 + 32 + l32]);
                        sh_out[node * 264 + head * 32 + l32] = f2bf(o);
                    }
                }
            }
            __syncthreads();

            // phase 3: ha[<=8 x 256] = sh_out @ Wlt^T + bl
            {
                f32x4 acc[4];
                #pragma unroll
                for (int ct = 0; ct < 4; ++ct) acc[ct] = (f32x4){0.f, 0.f, 0.f, 0.f};
                #pragma unroll 1
                for (int k0 = 0; k0 < 256; k0 += 32) {
                    bf16x8 a = *(const bf16x8*)(sh_out + mr * 264 + k0 + q * 8);
                    #pragma unroll
                    for (int ct = 0; ct < 4; ++ct) {
                        int col = w * 64 + ct * 16 + mr;
                        bf16x8 b = *(const bf16x8*)(Wlt + (size_t)col * 256 + k0 + q * 8);
                        acc[ct] = __builtin_amdgcn_mfma_f32_16x16x32_bf16(a, b, acc[ct], 0, 0, 0);
                    }
                }
                #pragma unroll
                for (int ct = 0; ct < 4; ++ct) {
                    int col = w * 64 + ct * 16 + mr;
                    float bv = bl[col];
                    #pragma unroll
                    for (int r = 0; r < 4; ++r) {
                        int row = q * 4 + r;
                        if (row < np) sh_ha[row * 264 + col] = f2bf(acc[ct][r] + bv);
                    }
                }
            }
            __syncthreads();

            // phase 4: iouf[<=8 x 1024] = sh_ha @ Bt2^T + biasU + xi (grouped)
            {
                f32x4 acc[16];
                #pragma unroll
                for (int ct = 0; ct < 16; ++ct) acc[ct] = (f32x4){0.f, 0.f, 0.f, 0.f};
                #pragma unroll 1
                for (int k0 = 0; k0 < 256; k0 += 32) {
                    bf16x8 a = *(const bf16x8*)(sh_ha + mr * 264 + k0 + q * 8);
                    #pragma unroll
                    for (int ct = 0; ct < 16; ++ct) {
                        int col = w * 256 + ct * 16 + mr;
                        bf16x8 b = *(const bf16x8*)(Bt2 + (size_t)col * 256 + k0 + q * 8);
                        acc[ct] = __builtin_amdgcn_mfma_f32_16x16x32_bf16(a, b, acc[ct], 0, 0, 0);
                    }
                }
                __syncthreads();  // sh_iouf overlaps sh_kv (done)
                #pragma unroll
                for (int ct = 0; ct < 16; ++ct) {
                    int col = w * 256 + ct * 16 + mr;
                    float bU = biasU[col];
                    #pragma unroll
                    for (int r = 0; r < 4; ++r) {
                        int row = q * 4 + r;
                        if (row < np)
                            sh_iouf[row * 1024 + col] =
                                acc[ct][r] + bU + bf2f(xi[(size_t)(s0 + p0 + row) * 1024 + col]);
                    }
                }
            }
            __syncthreads();

            // phase 5: cell (grouped: i,o,u,f at grp*128 + {0,32,64,96} + d)
            #pragma unroll 1
            for (int it = 0; it < 8; ++it) {
                int t = it * 256 + tid;
                if (t < np * 256) {
                    int node = t >> 8, j = t & 255;
                    int gcol = (j >> 5) * 128 + (j & 31);
                    float iv = sh_iouf[node * 1024 + gcol];
                    float ov = sh_iouf[node * 1024 + gcol + 32];
                    float uv = sh_iouf[node * 1024 + gcol + 64];
                    float fv = sigm(sh_iouf[node * 1024 + gcol + 96]);
                    float fc = 0.f;
                    #pragma unroll
                    for (int c = 0; c < 4; ++c)
                        fc += c_all[(size_t)(sc + 4 * (p0 + node) + c) * 256 + j] * fv;
                    float cn = sigm(iv) * ftanh(uv) + fc;
                    float hn = sigm(ov) * ftanh(cn);
                    size_t o = (size_t)(s0 + p0 + node) * 256 + j;
                    h_all[o] = hn;
                    c_all[o] = cn;
                    hb[o] = f2bf(hn);
                }
            }
        }
        if (l > 0) gridbar(bar + (5 - l), gridDim.x);
    }
}

// ---------------------------------------------------------------------------
// Prep kernels
// ---------------------------------------------------------------------------
__global__ __launch_bounds__(256) void conv_x(
    const float* __restrict__ x, short* __restrict__ xb, int n8)
{
    int t = blockIdx.x * 256 + threadIdx.x;
    if (t >= n8) return;
    float4v a = *(const float4v*)(x + (size_t)t * 8);
    float4v b = *(const float4v*)(x + (size_t)t * 8 + 4);
    bf16x8 o;
    o[0] = f2bf(a.x); o[1] = f2bf(a.y); o[2] = f2bf(a.z); o[3] = f2bf(a.w);
    o[4] = f2bf(b.x); o[5] = f2bf(b.y); o[6] = f2bf(b.z); o[7] = f2bf(b.w);
    *(bf16x8*)(xb + (size_t)t * 8) = o;
}

// Gate-grouped: col = grp*128 + gate*32 + d0, hidden = grp*32 + d0, gates iouf.
// Head-grouped KV: col = head*64 + kv*32 + d0, dim = head*32 + d0.
// Also zeroes the grid-barrier counters (stream-ordered before level_fused_all).
__global__ __launch_bounds__(256) void prep_weights(
    const float* __restrict__ W_iou, const float* __restrict__ W_f,
    const float* __restrict__ Uiou_w, const float* __restrict__ Uf_w,
    const float* __restrict__ Wk, const float* __restrict__ Wv,
    const float* __restrict__ Wq, const float* __restrict__ Wl,
    const float* __restrict__ b_iou, const float* __restrict__ b_f,
    const float* __restrict__ Uiou_b, const float* __restrict__ Uf_b,
    const float* __restrict__ bk, const float* __restrict__ bv,
    const float* __restrict__ bq,
    short* __restrict__ Bt1, short* __restrict__ Bt2, short* __restrict__ B3t,
    short* __restrict__ Wqt, short* __restrict__ Wlt,
    float* __restrict__ biasX, float* __restrict__ biasU,
    float* __restrict__ bias_kv, int* __restrict__ bar)
{
    int t = blockIdx.x * 256 + threadIdx.x;
    if (t < 262144) {
        int gc = t >> 8, k = t & 255;
        int within = gc & 127, gate = within >> 5, d = (gc >> 7) * 32 + (within & 31);
        float v = (gate < 3) ? W_iou[k * 768 + gate * 256 + d] : W_f[k * 256 + d];
        Bt1[t] = f2bf(v);
        return;
    }
    t -= 262144;
    if (t < 262144) {
        int gc = t >> 8, k = t & 255;
        int within = gc & 127, gate = within >> 5, d = (gc >> 7) * 32 + (within & 31);
        float v = (gate < 3) ? Uiou_w[k * 768 + gate * 256 + d] : Uf_w[k * 256 + d];
        Bt2[t] = f2bf(v);
        return;
    }
    t -= 262144;
    if (t < 131072) {
        int gc = t >> 8, k = t & 255;
        int head = gc >> 6, kv = (gc >> 5) & 1, d = head * 32 + (gc & 31);
        float v = kv ? Wv[k * 256 + d] : Wk[k * 256 + d];
        B3t[t] = f2bf(v);
        return;
    }
    t -= 131072;
    if (t < 65536) { int nn = t >> 8, k = t & 255; Wqt[t] = f2bf(Wq[k * 256 + nn]); return; }
    t -= 65536;
    if (t < 65536) { int nn = t >> 8, k = t & 255; Wlt[t] = f2bf(Wl[k * 256 + nn]); return; }
    t -= 65536;
    if (t < 1024) {
        int within = t & 127, gate = within >> 5, d = (t >> 7) * 32 + (within & 31);
        biasX[t] = (gate < 3) ? b_iou[gate * 256 + d] : b_f[d];
        return;
    }
    t -= 1024;
    if (t < 256) { biasX[1024 + t] = bq[t]; return; }
    t -= 256;
    if (t < 1024) {
        int within = t & 127, gate = within >> 5, d = (t >> 7) * 32 + (within & 31);
        biasU[t] = (gate < 3) ? Uiou_b[gate * 256 + d] : Uf_b[d];
        return;
    }
    t -= 1024;
    if (t < 512) {
        int head = t >> 6, kv = (t >> 5) & 1, d = head * 32 + (t & 31);
        bias_kv[t] = kv ? bv[d] : bk[d];
        return;
    }
    t -= 512;
    if (t < 8) { bar[t] = 0; return; }
}

// ---------------------------------------------------------------------------
static inline void launch_gemm(const short* A, const short* Bt, const float* bias,
                               const short* Cadd, void* C, int M, int N, int Kd,
                               int out_bf16, short* C2, int Nsplit, hipStream_t stream)
{
    dim3 grid(N / 128, (M + 127) / 128);
    gemm_bf16<<<grid, 256, 0, stream>>>(A, Bt, bias, Cadd, C, M, N, Kd, out_bf16,
                                        C2, Nsplit);
}

extern "C" void kernel_launch(void* const* d_in, const int* in_sizes, int n_in,
                              void* d_out, int out_size, void* d_ws, size_t ws_size,
                              hipStream_t stream)
{
    const float* x      = (const float*)d_in[0];
    const float* W_iou  = (const float*)d_in[1];
    const float* b_iou  = (const float*)d_in[2];
    const float* W_f    = (const float*)d_in[3];
    const float* b_f    = (const float*)d_in[4];
    const float* Wq     = (const float*)d_in[5];
    const float* bq     = (const float*)d_in[6];
    const float* Wk     = (const float*)d_in[7];
    const float* bk     = (const float*)d_in[8];
    const float* Wv     = (const float*)d_in[9];
    const float* bv     = (const float*)d_in[10];
    const float* Wl     = (const float*)d_in[11];
    const float* bl     = (const float*)d_in[12];
    const float* Uiou_w = (const float*)d_in[13];
    const float* Uiou_b = (const float*)d_in[14];
    const float* Uf_w   = (const float*)d_in[15];
    const float* Uf_b   = (const float*)d_in[16];

    float* h_all = (float*)d_out;
    float* c_all = h_all + (size_t)N_NODES_ * HS;

    char* p = (char*)d_ws;
    short* xb   = (short*)p; p += (size_t)N_NODES_ * 256 * 2;   // all-node x bf16
    short* hb   = (short*)p; p += (size_t)N_NODES_ * 256 * 2;   // all-node h bf16
    short* xi   = (short*)p; p += (size_t)21845 * 1024 * 2;     // internal x-preacts (grouped)
    short* qb   = (short*)p; p += (size_t)21845 * 256 * 2;      // all internal q
    short* outb = (short*)p; p += (size_t)16384 * 256 * 2;
    short* hab  = (short*)p; p += (size_t)16384 * 256 * 2;
    short* Bt1  = (short*)p; p += (size_t)1024 * 256 * 2;       // grouped iouf (x-side)
    short* Wqt  = (short*)p; p += (size_t)256 * 256 * 2;        // contiguous after Bt1
    short* Bt2  = (short*)p; p += (size_t)1024 * 256 * 2;       // grouped iouf (U-side)
    short* B3t  = (short*)p; p += (size_t)512 * 256 * 2;        // head-grouped KV
    short* Wlt  = (short*)p; p += (size_t)256 * 256 * 2;
    float* biasX   = (float*)p; p += 1280 * 4;                  // [grouped 1024 | bq 256]
    float* biasU   = (float*)p; p += 1024 * 4;
    float* bias_kv = (float*)p; p += 512 * 4;
    int*   bar     = (int*)p;   p += 8 * 4;                     // grid-barrier counters

    static const int starts[LEVELS_] = {0, 1, 5, 21, 85, 341, 1365, 5461, 21845};

    // prep
    {
        int n8 = N_NODES_ * 256 / 8;
        conv_x<<<(n8 + 255) / 256, 256, 0, stream>>>(x, xb, n8);
        int total = 262144 + 262144 + 131072 + 65536 + 65536 + 1024 + 256 + 1024 + 512 + 8;
        prep_weights<<<(total + 255) / 256, 256, 0, stream>>>(
            W_iou, W_f, Uiou_w, Uf_w, Wk, Wv, Wq, Wl,
            b_iou, b_f, Uiou_b, Uf_b, bk, bv, bq,
            Bt1, Bt2, B3t, Wqt, Wlt, biasX, biasU, bias_kv, bar);
    }

    // merged internal x-preact + q GEMM (N=1280, dual output)
    launch_gemm(xb, Bt1, biasX, nullptr, xi, 21845, 1280, 256, 1, qb, 1024, stream);

    // leaves: GEMM + fused cell (f-gate tiles skipped)
    {
        dim3 grid(8, 65536 / 128);
        gemm_cell<<<grid, 256, 0, stream>>>(
            xb + (size_t)21845 * 256, Bt1, biasX, nullptr, nullptr,
            h_all + (size_t)21845 * HS, c_all + (size_t)21845 * HS,
            hb + (size_t)21845 * HS, 65536);
    }

    // levels 7,6: kv_attn -> Wl gemm -> gemm_cell
    for (int l = 7; l >= 6; l--) {
        int n  = 1 << (2 * l);
        int s0 = starts[l];
        int sc = starts[l + 1];
        int nc = 4 * n;

        dim3 gkv(4, nc / 128);
        kv_attn<<<gkv, 256, 0, stream>>>(
            hb + (size_t)sc * 256, B3t, bias_kv, qb + (size_t)s0 * 256, outb);
        launch_gemm(outb, Wlt, bl, nullptr, hab, n, 256, 256, 1, nullptr, 0, stream);
        dim3 gc(8, n / 128);
        gemm_cell<<<gc, 256, 0, stream>>>(
            hab, Bt2, biasU, xi + (size_t)s0 * 1024, c_all + (size_t)sc * HS,
            h_all + (size_t)s0 * HS, c_all + (size_t)s0 * HS,
            hb + (size_t)s0 * HS, n);
    }

    // levels 5..0: ONE persistent kernel with internal grid barriers
    level_fused_all<<<128, 256, 0, stream>>>(
        hb, c_all, qb, xi, B3t, Wlt, Bt2, bias_kv, bl, biasU, h_all, bar);
}

// Round 5
// 842.975 us; speedup vs baseline: 1.0410x; 1.0410x over previous
//
#include <hip/hip_runtime.h>
#include <hip/hip_bf16.h>
#include <math.h>

constexpr int LEVELS_ = 9;
constexpr int N_NODES_ = 87381;
constexpr int HS = 256;
constexpr int N_HEADS_ = 8;

typedef __attribute__((ext_vector_type(8))) short bf16x8;
typedef __attribute__((ext_vector_type(4))) float f32x4;
typedef __attribute__((ext_vector_type(4))) float float4v;

__device__ __forceinline__ short f2bf(float f) {
    union { float f; unsigned u; } a; a.f = f;
    unsigned r = (a.u + 0x7fff + ((a.u >> 16) & 1)) >> 16;
    return (short)r;
}
__device__ __forceinline__ float bf2f(short s) {
    union { unsigned u; float f; } a; a.u = ((unsigned)(unsigned short)s) << 16;
    return a.f;
}
// fast transcendentals: v_exp_f32-based (error ~1e-6 rel, << bf16 rounding)
__device__ __forceinline__ float sigm(float x) { return 1.f / (1.f + __expf(-x)); }
__device__ __forceinline__ float ftanh(float x) {
    float e = __expf(-2.f * fabsf(x));
    float t = (1.f - e) / (1.f + e);
    return copysignf(t, x);
}

// async global->LDS, 16B per lane; LDS dest is wave-uniform base (+lane*16 by HW)
__device__ __forceinline__ void gl_lds16(const short* g, short* l) {
    __builtin_amdgcn_global_load_lds(
        (const __attribute__((address_space(1))) void*)g,
        (__attribute__((address_space(3))) void*)l, 16, 0, 0);
}

// bijective XCD-aware remap (m204)
__device__ __forceinline__ int xcd_swizzle(int flat, int nwg) {
    int q = nwg >> 3, r = nwg & 7;
    int xcd = flat & 7, idx = flat >> 3;
    int base = (xcd < r) ? xcd * (q + 1) : r * (q + 1) + (xcd - r) * q;
    return base + idx;
}

// ---------------------------------------------------------------------------
// Generic bf16 GEMM: C[M,N] = A @ Bt^T + bias (+Cadd), bf16 or f32 out.
// Optional dual output: cols >= Nsplit go to Cout2 (width N-Nsplit).
// 128x128 tile, BK=64, DOUBLE-BUFFERED 2-phase pipeline (T3 minimum recipe):
// stage(t+1) issued BEFORE compute(t); single __syncthreads per tile (its
// auto vmcnt(0) lands after compute -> HBM latency hidden under MFMA).
// REQUIREMENT: A readable for ceil(M/128)*128 rows; N%128==0; K%64==0.
// ---------------------------------------------------------------------------
__global__ __launch_bounds__(256) void gemm_bf16(
    const short* __restrict__ A, const short* __restrict__ Bt,
    const float* __restrict__ bias, const short* __restrict__ Cadd,
    void* __restrict__ Cout, int M, int N, int Kd, int out_bf16,
    short* __restrict__ Cout2, int Nsplit)
{
    __shared__ __align__(16) short smem[32768];   // 2 x (As 8192 | Bs 8192)

    const int tid = threadIdx.x;
    const int lane = tid & 63;
    const int w = tid >> 6;
    const int gx = gridDim.x;
    const int sw = xcd_swizzle(blockIdx.y * gx + blockIdx.x, gx * gridDim.y);
    const int row0 = (sw / gx) * 128;
    const int col0 = (sw % gx) * 128;
    const int wm = (w >> 1) * 64;
    const int wn = (w & 1) * 64;
    const int q = lane >> 4;
    const int mr = lane & 15;

    const int srl = lane >> 3;
    const int scs = ((lane & 7) ^ srl) * 8;

    auto stage = [&](int b, int k0) {
        short* As = smem + b * 16384;
        short* Bs = As + 8192;
        #pragma unroll
        for (int i = 0; i < 4; ++i) {
            int s = w * 4 + i;
            int r = s * 8 + srl;
            gl_lds16(A + (size_t)(row0 + r) * Kd + k0 + scs, As + s * 512);
            gl_lds16(Bt + (size_t)(col0 + r) * Kd + k0 + scs, Bs + s * 512);
        }
    };

    f32x4 acc[4][4];
    #pragma unroll
    for (int i = 0; i < 4; i++)
        #pragma unroll
        for (int j = 0; j < 4; j++) acc[i][j] = (f32x4){0.f, 0.f, 0.f, 0.f};

    stage(0, 0);
    __syncthreads();
    const int nk = Kd >> 6;
    for (int t = 0; t < nk; ++t) {
        if (t + 1 < nk) stage((t + 1) & 1, (t + 1) << 6);
        const short* As = smem + (t & 1) * 16384;
        const short* Bs = As + 8192;
        #pragma unroll
        for (int h = 0; h < 2; ++h) {
            bf16x8 af[4], bfr[4];
            #pragma unroll
            for (int i = 0; i < 4; ++i) {
                int r = wm + i * 16 + mr;
                af[i] = *(const bf16x8*)(As + r * 64 + ((h * 4 + q) ^ (mr & 7)) * 8);
            }
            #pragma unroll
            for (int j = 0; j < 4; ++j) {
                int r = wn + j * 16 + mr;
                bfr[j] = *(const bf16x8*)(Bs + r * 64 + ((h * 4 + q) ^ (mr & 7)) * 8);
            }
            #pragma unroll
            for (int i = 0; i < 4; ++i)
                #pragma unroll
                for (int j = 0; j < 4; ++j)
                    acc[i][j] = __builtin_amdgcn_mfma_f32_16x16x32_bf16(
                        af[i], bfr[j], acc[i][j], 0, 0, 0);
        }
        __syncthreads();
    }

    // resolve destination (dual-output support)
    short* dst;
    int width, colbase;
    if (Cout2 && col0 >= Nsplit) { dst = Cout2; colbase = col0 - Nsplit; width = N - Nsplit; }
    else { dst = (short*)Cout; colbase = col0; width = Cout2 ? Nsplit : N; }

    if (out_bf16) {
        short* Cs = smem;   // 128x128, fits in buffer 0 region
        #pragma unroll
        for (int j = 0; j < 4; ++j) {
            int col = wn + j * 16 + mr;
            float bv = bias ? bias[col0 + col] : 0.f;
            #pragma unroll
            for (int i = 0; i < 4; ++i) {
                #pragma unroll
                for (int r = 0; r < 4; ++r) {
                    int lr = wm + i * 16 + q * 4 + r;
                    float v = acc[i][j][r] + bv;
                    if (Cadd && row0 + lr < M)
                        v += bf2f(Cadd[(size_t)(row0 + lr) * width + colbase + col]);
                    Cs[lr * 128 + col] = f2bf(v);
                }
            }
        }
        __syncthreads();
        #pragma unroll
        for (int i = 0; i < 8; ++i) {
            int chunk = i * 256 + tid;
            int lr = chunk >> 4;
            int c8 = (chunk & 15) * 8;
            if (row0 + lr < M)
                *(bf16x8*)(dst + (size_t)(row0 + lr) * width + colbase + c8) =
                    *(const bf16x8*)(Cs + lr * 128 + c8);
        }
    } else {
        #pragma unroll
        for (int j = 0; j < 4; ++j) {
            int col = col0 + wn + j * 16 + mr;
            float bv = bias ? bias[col] : 0.f;
            #pragma unroll
            for (int i = 0; i < 4; ++i) {
                #pragma unroll
                for (int r = 0; r < 4; ++r) {
                    int grow = row0 + wm + i * 16 + q * 4 + r;
                    if (grow < M) {
                        size_t off = (size_t)grow * N + col;
                        float v = acc[i][j][r] + bv;
                        if (Cadd) v += bf2f(Cadd[off]);
                        ((float*)Cout)[off] = v;
                    }
                }
            }
        }
    }
}

// ---------------------------------------------------------------------------
// GEMM + fused LSTM cell. Bt is GATE-GROUPED: col = grp*128 + gate*32 + d,
// hidden dim = grp*32 + d, gates [i,o,u,f]. c_child==nullptr -> leaf
// (f-gate MFMAs + staging skipped). Double-buffered pipeline as above.
// ---------------------------------------------------------------------------
__global__ __launch_bounds__(256) void gemm_cell(
    const short* __restrict__ A, const short* __restrict__ Bt,
    const float* __restrict__ bias, const short* __restrict__ Cadd,
    const float* __restrict__ c_child,
    float* __restrict__ h_out, float* __restrict__ c_out,
    short* __restrict__ hb_out, int M)
{
    __shared__ __align__(16) short smem[32768];   // dbuf; Cs (128x136) overlays

    const int tid = threadIdx.x;
    const int lane = tid & 63;
    const int w = tid >> 6;
    const int gx = gridDim.x;
    const int sw = xcd_swizzle(blockIdx.y * gx + blockIdx.x, gx * gridDim.y);
    const int row0 = (sw / gx) * 128;
    const int bxs = sw % gx;
    const int col0 = bxs * 128;
    const int wm = (w >> 1) * 64;
    const int wn = (w & 1) * 64;
    const int q = lane >> 4;
    const int mr = lane & 15;

    const int srl = lane >> 3;
    const int scs = ((lane & 7) ^ srl) * 8;

    const bool leaf = (c_child == nullptr);
    const int jn = (leaf && wn == 64) ? 2 : 4;   // skip f-gate tiles for leaves

    auto stage = [&](int b, int k0) {
        short* As = smem + b * 16384;
        short* Bs = As + 8192;
        #pragma unroll
        for (int i = 0; i < 4; ++i) {
            int s = w * 4 + i;
            int r = s * 8 + srl;
            gl_lds16(A + (size_t)(row0 + r) * 256 + k0 + scs, As + s * 512);
            if (!(leaf && s >= 12))   // Bs rows 96..127 = f-gate cols: unused
                gl_lds16(Bt + (size_t)(col0 + r) * 256 + k0 + scs, Bs + s * 512);
        }
    };

    f32x4 acc[4][4];
    #pragma unroll
    for (int i = 0; i < 4; i++)
        #pragma unroll
        for (int j = 0; j < 4; j++) acc[i][j] = (f32x4){0.f, 0.f, 0.f, 0.f};

    stage(0, 0);
    __syncthreads();
    for (int t = 0; t < 4; ++t) {
        if (t + 1 < 4) stage((t + 1) & 1, (t + 1) << 6);
        const short* As = smem + (t & 1) * 16384;
        const short* Bs = As + 8192;
        #pragma unroll
        for (int h = 0; h < 2; ++h) {
            bf16x8 af[4], bfr[4];
            #pragma unroll
            for (int i = 0; i < 4; ++i) {
                int r = wm + i * 16 + mr;
                af[i] = *(const bf16x8*)(As + r * 64 + ((h * 4 + q) ^ (mr & 7)) * 8);
            }
            #pragma unroll
            for (int j = 0; j < 4; ++j)
                if (j < jn) {
                    int r = wn + j * 16 + mr;
                    bfr[j] = *(const bf16x8*)(Bs + r * 64 + ((h * 4 + q) ^ (mr & 7)) * 8);
                }
            #pragma unroll
            for (int i = 0; i < 4; ++i)
                #pragma unroll
                for (int j = 0; j < 4; ++j)
                    if (j < jn)
                        acc[i][j] = __builtin_amdgcn_mfma_f32_16x16x32_bf16(
                            af[i], bfr[j], acc[i][j], 0, 0, 0);
        }
        __syncthreads();
    }

    // preacts -> Cs (bf16, stride 136 to spread 4-gate strided reads)
    short* Cs = smem;
    #pragma unroll
    for (int j = 0; j < 4; ++j) {
        int col = wn + j * 16 + mr;
        float bv = bias[col0 + col];
        #pragma unroll
        for (int i = 0; i < 4; ++i) {
            #pragma unroll
            for (int r = 0; r < 4; ++r) {
                int lr = wm + i * 16 + q * 4 + r;
                float v = acc[i][j][r] + bv;
                if (Cadd && row0 + lr < M)
                    v += bf2f(Cadd[(size_t)(row0 + lr) * 1024 + col0 + col]);
                Cs[lr * 136 + col] = f2bf(v);
            }
        }
    }
    __syncthreads();

    const int hd0 = bxs * 32;
    #pragma unroll 1
    for (int it = 0; it < 2; ++it) {
        int chunk = it * 256 + tid;       // 512 chunks: 128 rows x 4 d8-slots
        int row = chunk >> 2;
        int d8 = (chunk & 3) * 8;
        int gp = row0 + row;
        if (gp < M) {
            bf16x8 vi = *(const bf16x8*)(Cs + row * 136 + d8);
            bf16x8 vo = *(const bf16x8*)(Cs + row * 136 + 32 + d8);
            bf16x8 vu = *(const bf16x8*)(Cs + row * 136 + 64 + d8);
            float fc[8] = {0.f, 0.f, 0.f, 0.f, 0.f, 0.f, 0.f, 0.f};
            if (!leaf) {
                bf16x8 vf = *(const bf16x8*)(Cs + row * 136 + 96 + d8);
                #pragma unroll
                for (int c = 0; c < 4; ++c) {
                    const float* cp = c_child + (size_t)(4 * gp + c) * 256 + hd0 + d8;
                    float4v a = *(const float4v*)cp;
                    float4v b = *(const float4v*)(cp + 4);
                    #pragma unroll
                    for (int e = 0; e < 4; ++e) { fc[e] += a[e]; fc[4 + e] += b[e]; }
                }
                #pragma unroll
                for (int e = 0; e < 8; ++e) fc[e] *= sigm(bf2f(vf[e]));
            }
            float4v hv[2], cv[2];
            bf16x8 hbv;
            #pragma unroll
            for (int e = 0; e < 8; ++e) {
                float cn = sigm(bf2f(vi[e])) * ftanh(bf2f(vu[e])) + fc[e];
                float hn = sigm(bf2f(vo[e])) * ftanh(cn);
                hv[e >> 2][e & 3] = hn;
                cv[e >> 2][e & 3] = cn;
                hbv[e] = f2bf(hn);
            }
            size_t o = (size_t)gp * 256 + hd0 + d8;
            *(float4v*)(h_out + o) = hv[0]; *(float4v*)(h_out + o + 4) = hv[1];
            *(float4v*)(c_out + o) = cv[0]; *(float4v*)(c_out + o + 4) = cv[1];
            *(bf16x8*)(hb_out + o) = hbv;
        }
    }
}

// ---------------------------------------------------------------------------
// KV GEMM + fused attention. B3t HEAD-GROUPED: col = head*64 + kv*32 + d.
// Block (bx,by): child rows by*128 (=32 parents), heads 2bx,2bx+1 (K+V).
// Double-buffered pipeline.
// ---------------------------------------------------------------------------
__global__ __launch_bounds__(256) void kv_attn(
    const short* __restrict__ A,       // hb + sc*256 (children)
    const short* __restrict__ B3t,     // grouped [512][256]
    const float* __restrict__ bias_kv, // grouped [512]
    const short* __restrict__ qb_lvl,  // qb + s0*256
    short* __restrict__ outb)
{
    __shared__ __align__(16) short smem[32768 + 2048]; // dbuf -> Cs ; sh_o
    short* sh_o = smem + 32768;

    const int tid = threadIdx.x;
    const int lane = tid & 63;
    const int w = tid >> 6;
    const int gx = gridDim.x;   // 4
    const int sw = xcd_swizzle(blockIdx.y * gx + blockIdx.x, gx * gridDim.y);
    const int byq = sw / gx;
    const int colb = sw % gx;          // heads 2*colb, 2*colb+1
    const int row0 = byq * 128;
    const int col0 = colb * 128;
    const int wm = (w >> 1) * 64;
    const int wn = (w & 1) * 64;
    const int q = lane >> 4;
    const int mr = lane & 15;

    const int srl = lane >> 3;
    const int scs = ((lane & 7) ^ srl) * 8;

    auto stage = [&](int b, int k0) {
        short* As = smem + b * 16384;
        short* Bs = As + 8192;
        #pragma unroll
        for (int i = 0; i < 4; ++i) {
            int s = w * 4 + i;
            int r = s * 8 + srl;
            gl_lds16(A + (size_t)(row0 + r) * 256 + k0 + scs, As + s * 512);
            gl_lds16(B3t + (size_t)(col0 + r) * 256 + k0 + scs, Bs + s * 512);
        }
    };

    f32x4 acc[4][4];
    #pragma unroll
    for (int i = 0; i < 4; i++)
        #pragma unroll
        for (int j = 0; j < 4; j++) acc[i][j] = (f32x4){0.f, 0.f, 0.f, 0.f};

    stage(0, 0);
    __syncthreads();
    for (int t = 0; t < 4; ++t) {
        if (t + 1 < 4) stage((t + 1) & 1, (t + 1) << 6);
        const short* As = smem + (t & 1) * 16384;
        const short* Bs = As + 8192;
        #pragma unroll
        for (int h = 0; h < 2; ++h) {
            bf16x8 af[4], bfr[4];
            #pragma unroll
            for (int i = 0; i < 4; ++i) {
                int r = wm + i * 16 + mr;
                af[i] = *(const bf16x8*)(As + r * 64 + ((h * 4 + q) ^ (mr & 7)) * 8);
            }
            #pragma unroll
            for (int j = 0; j < 4; ++j) {
                int r = wn + j * 16 + mr;
                bfr[j] = *(const bf16x8*)(Bs + r * 64 + ((h * 4 + q) ^ (mr & 7)) * 8);
            }
            #pragma unroll
            for (int i = 0; i < 4; ++i)
                #pragma unroll
                for (int j = 0; j < 4; ++j)
                    acc[i][j] = __builtin_amdgcn_mfma_f32_16x16x32_bf16(
                        af[i], bfr[j], acc[i][j], 0, 0, 0);
        }
        __syncthreads();
    }

    // KV tile -> Cs (bf16, 128x128)
    short* Cs = smem;
    #pragma unroll
    for (int j = 0; j < 4; ++j) {
        int col = wn + j * 16 + mr;
        float bv = bias_kv[col0 + col];
        #pragma unroll
        for (int i = 0; i < 4; ++i) {
            #pragma unroll
            for (int r = 0; r < 4; ++r) {
                int lr = wm + i * 16 + q * 4 + r;
                Cs[lr * 128 + col] = f2bf(acc[i][j][r] + bv);
            }
        }
    }
    __syncthreads();

    // attention: 32 parents x 2 heads = 64 pairs, 32 lanes each
    const int p0 = byq * 32;
    const int grp0 = tid >> 5;
    const int l32 = tid & 31;
    #pragma unroll 1
    for (int it = 0; it < 8; ++it) {
        int pair = it * 8 + grp0;         // 0..63
        int pl = pair >> 1, hh = pair & 1;
        float qv = bf2f(qb_lvl[(size_t)(p0 + pl) * 256 + (colb * 2 + hh) * 32 + l32]);
        float logit[4];
        #pragma unroll
        for (int c = 0; c < 4; ++c) {
            float pch = qv * bf2f(Cs[(4 * pl + c) * 128 + hh * 64 + l32]);
            #pragma unroll
            for (int off = 16; off >= 1; off >>= 1)
                pch += __shfl_xor(pch, off, 32);
            logit[c] = pch * 0.17677669529663687f;
        }
        float mx = fmaxf(fmaxf(logit[0], logit[1]), fmaxf(logit[2], logit[3]));
        float e[4], s = 0.f;
        #pragma unroll
        for (int c = 0; c < 4; ++c) { e[c] = __expf(logit[c] - mx); s += e[c]; }
        float inv = 1.f / s;
        float o = 0.f;
        #pragma unroll
        for (int c = 0; c < 4; ++c)
            o += (e[c] * inv) * bf2f(Cs[(4 * pl + c) * 128 + hh * 64 + 32 + l32]);
        sh_o[pl * 64 + hh * 32 + l32] = f2bf(o);
    }
    __syncthreads();
    {
        int r = tid >> 3, c8 = (tid & 7) * 8;    // 32 rows x 64 cols
        *(bf16x8*)(outb + (size_t)(p0 + r) * 256 + colb * 64 + c8) =
            *(const bf16x8*)(sh_o + r * 64 + c8);
    }
}

// ---------------------------------------------------------------------------
// Fused level kernel for n <= 1024 (grouped layouts). Per-level launch.
// ---------------------------------------------------------------------------
__global__ __launch_bounds__(256) void level_fused(
    const short* __restrict__ hb, const float* __restrict__ c_all,
    const short* __restrict__ qb, const short* __restrict__ xi,
    const short* __restrict__ B3t, const short* __restrict__ Wlt,
    const short* __restrict__ Bt2,
    const float* __restrict__ bias_kv, const float* __restrict__ bl,
    const float* __restrict__ biasU,
    float* __restrict__ h_all, float* __restrict__ c_out_g,
    short* __restrict__ hb_out, int s0, int sc, int n)
{
    __shared__ __align__(16) char smem[50176];
    short* sh_h    = (short*)smem;             // 32 x 264
    short* sh_kv   = (short*)(smem + 16896);   // 32 x 520 (grouped cols)
    short* sh_out  = (short*)smem;             // 16 x 264 (reuse sh_h)
    short* sh_ha   = (short*)(smem + 8448);    // 16 x 264
    float* sh_iouf = (float*)(smem + 16896);   // 8 x 1024 (grouped cols)

    const int tid = threadIdx.x;
    const int lane = tid & 63;
    const int w = tid >> 6;
    const int q = lane >> 4;
    const int mr = lane & 15;
    const int p0 = blockIdx.x * 8;
    const int np = (n - p0 < 8) ? (n - p0) : 8;
    const int nch = 4 * np;

    // phase 0: stage children h
    #pragma unroll
    for (int i = 0; i < 4; ++i) {
        int chunk = i * 256 + tid;
        int r = chunk >> 5;
        int c8 = (chunk & 31) * 8;
        bf16x8 v = {};
        if (r < nch) v = *(const bf16x8*)(hb + (size_t)(sc + 4 * p0 + r) * 256 + c8);
        *(bf16x8*)(sh_h + r * 264 + c8) = v;
    }
    __syncthreads();

    // phase 1: KV[32x512] = sh_h @ B3t^T + bias_kv (grouped cols)
    {
        f32x4 acc[2][8];
        #pragma unroll
        for (int rt = 0; rt < 2; ++rt)
            #pragma unroll
            for (int ct = 0; ct < 8; ++ct) acc[rt][ct] = (f32x4){0.f, 0.f, 0.f, 0.f};
        #pragma unroll 1
        for (int k0 = 0; k0 < 256; k0 += 32) {
            bf16x8 a0 = *(const bf16x8*)(sh_h + mr * 264 + k0 + q * 8);
            bf16x8 a1 = *(const bf16x8*)(sh_h + (16 + mr) * 264 + k0 + q * 8);
            #pragma unroll
            for (int ct = 0; ct < 8; ++ct) {
                int col = w * 128 + ct * 16 + mr;
                bf16x8 b = *(const bf16x8*)(B3t + (size_t)col * 256 + k0 + q * 8);
                acc[0][ct] = __builtin_amdgcn_mfma_f32_16x16x32_bf16(a0, b, acc[0][ct], 0, 0, 0);
                acc[1][ct] = __builtin_amdgcn_mfma_f32_16x16x32_bf16(a1, b, acc[1][ct], 0, 0, 0);
            }
        }
        #pragma unroll
        for (int ct = 0; ct < 8; ++ct) {
            int col = w * 128 + ct * 16 + mr;
            float bv = bias_kv[col];
            #pragma unroll
            for (int rt = 0; rt < 2; ++rt)
                #pragma unroll
                for (int r = 0; r < 4; ++r) {
                    int row = rt * 16 + q * 4 + r;
                    sh_kv[row * 520 + col] = f2bf(acc[rt][ct][r] + bv);
                }
        }
    }
    __syncthreads();

    // phase 2: attention (K at head*64, V at head*64+32) -> sh_out
    {
        const int grp0 = tid >> 5;
        const int l32 = tid & 31;
        #pragma unroll 1
        for (int it = 0; it < 8; ++it) {
            int grp = it * 8 + grp0;
            int node = grp >> 3, head = grp & 7;
            if (node < np) {
                float qv = bf2f(qb[(size_t)(s0 + p0 + node) * 256 + head * 32 + l32]);
                float logit[4];
                #pragma unroll
                for (int c = 0; c < 4; ++c) {
                    float p = qv * bf2f(sh_kv[(4 * node + c) * 520 + head * 64 + l32]);
                    #pragma unroll
                    for (int off = 16; off >= 1; off >>= 1)
                        p += __shfl_xor(p, off, 32);
                    logit[c] = p * 0.17677669529663687f;
                }
                float mx = fmaxf(fmaxf(logit[0], logit[1]), fmaxf(logit[2], logit[3]));
                float e[4], s = 0.f;
                #pragma unroll
                for (int c = 0; c < 4; ++c) { e[c] = __expf(logit[c] - mx); s += e[c]; }
                float inv = 1.f / s;
                float o = 0.f;
                #pragma unroll
                for (int c = 0; c < 4; ++c)
                    o += (e[c] * inv) * bf2f(sh_kv[(4 * node + c) * 520 + head * 64 + 32 + l32]);
                sh_out[node * 264 + head * 32 + l32] = f2bf(o);
            }
        }
    }
    __syncthreads();

    // phase 3: ha[<=8 x 256] = sh_out @ Wlt^T + bl (standard layout)
    {
        f32x4 acc[4];
        #pragma unroll
        for (int ct = 0; ct < 4; ++ct) acc[ct] = (f32x4){0.f, 0.f, 0.f, 0.f};
        #pragma unroll 1
        for (int k0 = 0; k0 < 256; k0 += 32) {
            bf16x8 a = *(const bf16x8*)(sh_out + mr * 264 + k0 + q * 8);
            #pragma unroll
            for (int ct = 0; ct < 4; ++ct) {
                int col = w * 64 + ct * 16 + mr;
                bf16x8 b = *(const bf16x8*)(Wlt + (size_t)col * 256 + k0 + q * 8);
                acc[ct] = __builtin_amdgcn_mfma_f32_16x16x32_bf16(a, b, acc[ct], 0, 0, 0);
            }
        }
        #pragma unroll
        for (int ct = 0; ct < 4; ++ct) {
            int col = w * 64 + ct * 16 + mr;
            float bv = bl[col];
            #pragma unroll
            for (int r = 0; r < 4; ++r) {
                int row = q * 4 + r;
                if (row < np) sh_ha[row * 264 + col] = f2bf(acc[ct][r] + bv);
            }
        }
    }
    __syncthreads();

    // phase 4: iouf[<=8 x 1024] = sh_ha @ Bt2^T + biasU + xi (grouped cols)
    {
        f32x4 acc[16];
        #pragma unroll
        for (int ct = 0; ct < 16; ++ct) acc[ct] = (f32x4){0.f, 0.f, 0.f, 0.f};
        #pragma unroll 1
        for (int k0 = 0; k0 < 256; k0 += 32) {
            bf16x8 a = *(const bf16x8*)(sh_ha + mr * 264 + k0 + q * 8);
            #pragma unroll
            for (int ct = 0; ct < 16; ++ct) {
                int col = w * 256 + ct * 16 + mr;
                bf16x8 b = *(const bf16x8*)(Bt2 + (size_t)col * 256 + k0 + q * 8);
                acc[ct] = __builtin_amdgcn_mfma_f32_16x16x32_bf16(a, b, acc[ct], 0, 0, 0);
            }
        }
        __syncthreads();  // sh_iouf overlaps sh_kv (done); sh_ha reads complete
        #pragma unroll
        for (int ct = 0; ct < 16; ++ct) {
            int col = w * 256 + ct * 16 + mr;
            float bU = biasU[col];
            #pragma unroll
            for (int r = 0; r < 4; ++r) {
                int row = q * 4 + r;
                if (row < np)
                    sh_iouf[row * 1024 + col] =
                        acc[ct][r] + bU + bf2f(xi[(size_t)(s0 + p0 + row) * 1024 + col]);
            }
        }
    }
    __syncthreads();

    // phase 5: cell (grouped: i,o,u,f at grp*128 + {0,32,64,96} + d)
    #pragma unroll 1
    for (int it = 0; it < 8; ++it) {
        int t = it * 256 + tid;
        if (t < np * 256) {
            int node = t >> 8, j = t & 255;
            int gcol = (j >> 5) * 128 + (j & 31);
            float iv = sh_iouf[node * 1024 + gcol];
            float ov = sh_iouf[node * 1024 + gcol + 32];
            float uv = sh_iouf[node * 1024 + gcol + 64];
            float fv = sigm(sh_iouf[node * 1024 + gcol + 96]);
            float fc = 0.f;
            #pragma unroll
            for (int c = 0; c < 4; ++c)
                fc += c_all[(size_t)(sc + 4 * (p0 + node) + c) * 256 + j] * fv;
            float cn = sigm(iv) * ftanh(uv) + fc;
            float hn = sigm(ov) * ftanh(cn);
            size_t o = (size_t)(s0 + p0 + node) * 256 + j;
            h_all[o] = hn;
            c_out_g[o] = cn;
            hb_out[o] = f2bf(hn);
        }
    }
}

// ---------------------------------------------------------------------------
// Prep kernels
// ---------------------------------------------------------------------------
__global__ __launch_bounds__(256) void conv_x(
    const float* __restrict__ x, short* __restrict__ xb, int n8)
{
    int t = blockIdx.x * 256 + threadIdx.x;
    if (t >= n8) return;
    float4v a = *(const float4v*)(x + (size_t)t * 8);
    float4v b = *(const float4v*)(x + (size_t)t * 8 + 4);
    bf16x8 o;
    o[0] = f2bf(a.x); o[1] = f2bf(a.y); o[2] = f2bf(a.z); o[3] = f2bf(a.w);
    o[4] = f2bf(b.x); o[5] = f2bf(b.y); o[6] = f2bf(b.z); o[7] = f2bf(b.w);
    *(bf16x8*)(xb + (size_t)t * 8) = o;
}

// Gate-grouped: col = grp*128 + gate*32 + d0, hidden = grp*32 + d0, gates iouf.
// Head-grouped KV: col = head*64 + kv*32 + d0, dim = head*32 + d0.
__global__ __launch_bounds__(256) void prep_weights(
    const float* __restrict__ W_iou, const float* __restrict__ W_f,
    const float* __restrict__ Uiou_w, const float* __restrict__ Uf_w,
    const float* __restrict__ Wk, const float* __restrict__ Wv,
    const float* __restrict__ Wq, const float* __restrict__ Wl,
    const float* __restrict__ b_iou, const float* __restrict__ b_f,
    const float* __restrict__ Uiou_b, const float* __restrict__ Uf_b,
    const float* __restrict__ bk, const float* __restrict__ bv,
    const float* __restrict__ bq,
    short* __restrict__ Bt1, short* __restrict__ Bt2, short* __restrict__ B3t,
    short* __restrict__ Wqt, short* __restrict__ Wlt,
    float* __restrict__ biasX, float* __restrict__ biasU,
    float* __restrict__ bias_kv)
{
    int t = blockIdx.x * 256 + threadIdx.x;
    if (t < 262144) {
        int gc = t >> 8, k = t & 255;
        int within = gc & 127, gate = within >> 5, d = (gc >> 7) * 32 + (within & 31);
        float v = (gate < 3) ? W_iou[k * 768 + gate * 256 + d] : W_f[k * 256 + d];
        Bt1[t] = f2bf(v);
        return;
    }
    t -= 262144;
    if (t < 262144) {
        int gc = t >> 8, k = t & 255;
        int within = gc & 127, gate = within >> 5, d = (gc >> 7) * 32 + (within & 31);
        float v = (gate < 3) ? Uiou_w[k * 768 + gate * 256 + d] : Uf_w[k * 256 + d];
        Bt2[t] = f2bf(v);
        return;
    }
    t -= 262144;
    if (t < 131072) {
        int gc = t >> 8, k = t & 255;
        int head = gc >> 6, kv = (gc >> 5) & 1, d = head * 32 + (gc & 31);
        float v = kv ? Wv[k * 256 + d] : Wk[k * 256 + d];
        B3t[t] = f2bf(v);
        return;
    }
    t -= 131072;
    if (t < 65536) { int nn = t >> 8, k = t & 255; Wqt[t] = f2bf(Wq[k * 256 + nn]); return; }
    t -= 65536;
    if (t < 65536) { int nn = t >> 8, k = t & 255; Wlt[t] = f2bf(Wl[k * 256 + nn]); return; }
    t -= 65536;
    if (t < 1024) {
        int within = t & 127, gate = within >> 5, d = (t >> 7) * 32 + (within & 31);
        biasX[t] = (gate < 3) ? b_iou[gate * 256 + d] : b_f[d];
        return;
    }
    t -= 1024;
    if (t < 256) { biasX[1024 + t] = bq[t]; return; }
    t -= 256;
    if (t < 1024) {
        int within = t & 127, gate = within >> 5, d = (t >> 7) * 32 + (within & 31);
        biasU[t] = (gate < 3) ? Uiou_b[gate * 256 + d] : Uf_b[d];
        return;
    }
    t -= 1024;
    if (t < 512) {
        int head = t >> 6, kv = (t >> 5) & 1, d = head * 32 + (t & 31);
        bias_kv[t] = kv ? bv[d] : bk[d];
        return;
    }
}

// ---------------------------------------------------------------------------
static inline void launch_gemm(const short* A, const short* Bt, const float* bias,
                               const short* Cadd, void* C, int M, int N, int Kd,
                               int out_bf16, short* C2, int Nsplit, hipStream_t stream)
{
    dim3 grid(N / 128, (M + 127) / 128);
    gemm_bf16<<<grid, 256, 0, stream>>>(A, Bt, bias, Cadd, C, M, N, Kd, out_bf16,
                                        C2, Nsplit);
}

extern "C" void kernel_launch(void* const* d_in, const int* in_sizes, int n_in,
                              void* d_out, int out_size, void* d_ws, size_t ws_size,
                              hipStream_t stream)
{
    const float* x      = (const float*)d_in[0];
    const float* W_iou  = (const float*)d_in[1];
    const float* b_iou  = (const float*)d_in[2];
    const float* W_f    = (const float*)d_in[3];
    const float* b_f    = (const float*)d_in[4];
    const float* Wq     = (const float*)d_in[5];
    const float* bq     = (const float*)d_in[6];
    const float* Wk     = (const float*)d_in[7];
    const float* bk     = (const float*)d_in[8];
    const float* Wv     = (const float*)d_in[9];
    const float* bv     = (const float*)d_in[10];
    const float* Wl     = (const float*)d_in[11];
    const float* bl     = (const float*)d_in[12];
    const float* Uiou_w = (const float*)d_in[13];
    const float* Uiou_b = (const float*)d_in[14];
    const float* Uf_w   = (const float*)d_in[15];
    const float* Uf_b   = (const float*)d_in[16];

    float* h_all = (float*)d_out;
    float* c_all = h_all + (size_t)N_NODES_ * HS;

    char* p = (char*)d_ws;
    short* xb   = (short*)p; p += (size_t)N_NODES_ * 256 * 2;   // all-node x bf16
    short* hb   = (short*)p; p += (size_t)N_NODES_ * 256 * 2;   // all-node h bf16
    short* xi   = (short*)p; p += (size_t)21845 * 1024 * 2;     // internal x-preacts (grouped)
    short* qb   = (short*)p; p += (size_t)21845 * 256 * 2;      // all internal q
    short* outb = (short*)p; p += (size_t)16384 * 256 * 2;
    short* hab  = (short*)p; p += (size_t)16384 * 256 * 2;
    short* Bt1  = (short*)p; p += (size_t)1024 * 256 * 2;       // grouped iouf (x-side)
    short* Wqt  = (short*)p; p += (size_t)256 * 256 * 2;        // contiguous after Bt1
    short* Bt2  = (short*)p; p += (size_t)1024 * 256 * 2;       // grouped iouf (U-side)
    short* B3t  = (short*)p; p += (size_t)512 * 256 * 2;        // head-grouped KV
    short* Wlt  = (short*)p; p += (size_t)256 * 256 * 2;
    float* biasX   = (float*)p; p += 1280 * 4;                  // [grouped 1024 | bq 256]
    float* biasU   = (float*)p; p += 1024 * 4;
    float* bias_kv = (float*)p; p += 512 * 4;

    static const int starts[LEVELS_] = {0, 1, 5, 21, 85, 341, 1365, 5461, 21845};

    // prep
    {
        int n8 = N_NODES_ * 256 / 8;
        conv_x<<<(n8 + 255) / 256, 256, 0, stream>>>(x, xb, n8);
        int total = 262144 + 262144 + 131072 + 65536 + 65536 + 1024 + 256 + 1024 + 512;
        prep_weights<<<(total + 255) / 256, 256, 0, stream>>>(
            W_iou, W_f, Uiou_w, Uf_w, Wk, Wv, Wq, Wl,
            b_iou, b_f, Uiou_b, Uf_b, bk, bv, bq,
            Bt1, Bt2, B3t, Wqt, Wlt, biasX, biasU, bias_kv);
    }

    // merged internal x-preact + q GEMM (N=1280, dual output)
    launch_gemm(xb, Bt1, biasX, nullptr, xi, 21845, 1280, 256, 1, qb, 1024, stream);

    // leaves: GEMM + fused cell (f-gate tiles skipped)
    {
        dim3 grid(8, 65536 / 128);
        gemm_cell<<<grid, 256, 0, stream>>>(
            xb + (size_t)21845 * 256, Bt1, biasX, nullptr, nullptr,
            h_all + (size_t)21845 * HS, c_all + (size_t)21845 * HS,
            hb + (size_t)21845 * HS, 65536);
    }

    // levels 7,6: kv_attn -> Wl gemm -> gemm_cell
    for (int l = 7; l >= 6; l--) {
        int n  = 1 << (2 * l);
        int s0 = starts[l];
        int sc = starts[l + 1];
        int nc = 4 * n;

        dim3 gkv(4, nc / 128);
        kv_attn<<<gkv, 256, 0, stream>>>(
            hb + (size_t)sc * 256, B3t, bias_kv, qb + (size_t)s0 * 256, outb);
        launch_gemm(outb, Wlt, bl, nullptr, hab, n, 256, 256, 1, nullptr, 0, stream);
        dim3 gc(8, n / 128);
        gemm_cell<<<gc, 256, 0, stream>>>(
            hab, Bt2, biasU, xi + (size_t)s0 * 1024, c_all + (size_t)sc * HS,
            h_all + (size_t)s0 * HS, c_all + (size_t)s0 * HS,
            hb + (size_t)s0 * HS, n);
    }

    // levels 5..0: per-level fused launches
    for (int l = 5; l >= 0; l--) {
        int n  = 1 << (2 * l);
        int s0 = starts[l];
        int sc = starts[l + 1];
        int blocks = (n + 7) / 8;
        level_fused<<<blocks, 256, 0, stream>>>(
            hb, c_all, qb, xi, B3t, Wlt, Bt2, bias_kv, bl, biasU,
            h_all, c_all, hb, s0, sc, n);
    }
}